// Round 9
// baseline (60.478 us; speedup 1.0000x reference)
//
#include <hip/hip_runtime.h>
#include <hip/hip_bf16.h>

#define N_PTS 4096
#define D_EMB 64
#define BTILE 64                     // block tile (4 waves of 32x32)
#define NWAVE ((N_PTS / BTILE) * (N_PTS / BTILE) * 4)   // 16384 waves

typedef __attribute__((ext_vector_type(8))) short bf16x8;  // 8 bf16 = 4 VGPR
typedef __attribute__((ext_vector_type(4))) float f32x4;   // MFMA 16x16 acc

// ---------------------------------------------------------------------------
// Fused prep: bf16 hi/lo split + exact f32 row squared-norms.
// ---------------------------------------------------------------------------
__global__ void prep_kernel(const float* __restrict__ mapping,
                            ushort* __restrict__ Mhi,
                            ushort* __restrict__ Mlo,
                            float* __restrict__ nrm) {
  const int row = blockIdx.x;
  const int l = threadIdx.x;          // 0..63
  const int idx = row * D_EMB + l;
  const float x = mapping[idx];
  __hip_bfloat16 h = __float2bfloat16(x);
  const float hf = __bfloat162float(h);
  __hip_bfloat16 lo = __float2bfloat16(x - hf);
  Mhi[idx] = *reinterpret_cast<ushort*>(&h);
  Mlo[idx] = *reinterpret_cast<ushort*>(&lo);
  float s = x * x;
  #pragma unroll
  for (int off = 32; off > 0; off >>= 1) s += __shfl_down(s, off);
  if (l == 0) nrm[row] = s;
}

// ---------------------------------------------------------------------------
// MFMA gram (operand-swapped) + fused distortion partial sums.
// dot = Hj.Hi + Hj.Li + Lj.Hi  (Li.Lj dropped; absmax 0.0 since R6).
//
// R8 post-mortem: 64x64/wave left only ~6 waves/CU (Occupancy 19%,
// VALU 11%, Mfma 3%) -> pure latency bound; float4 D-epilogue moved
// nothing. THIS round: 32x32 per wave (acc 16 VGPR, ~80 total), 4096
// blocks = 64 waves/CU demanded -> 3-4x TLP to cover load latency.
//
// Layout (HW-verified by absmax 0.0 in R8):
//   acc[m][n] = mfma(fragJ, fragI): out row gj = j0+n*16+kg*4+reg (4
//   consecutive -> float4 D/nrm loads), out col gi = i0+m*16+r16.
// R7 lesson: load all fragments of a k-step up-front (8 independent
// loads), never phase them into serialized load->mfma pairs.
// R5 lesson: contention-free per-wave partial writes (NO atomics).
// R2/R3 lesson: no min-waves launch_bounds arg (forced spills).
// ---------------------------------------------------------------------------
__global__ __launch_bounds__(256) void distortion_main(
    const ushort* __restrict__ Mhi, const ushort* __restrict__ Mlo,
    const float* __restrict__ Dm, const float* __restrict__ nrm,
    double* __restrict__ part) {
  const int t = threadIdx.x;
  const int w = t >> 6, l = t & 63;
  const int r16 = l & 15;        // fragment row/col within 16
  const int kg = l >> 4;         // k-group 0..3
  const int wr = w >> 1, wc = w & 1;
  const int i0 = blockIdx.y * BTILE + wr * 32;   // wave i-panel base
  const int j0 = blockIdx.x * BTILE + wc * 32;   // wave j-panel base

  f32x4 acc[2][2] = {};  // cols gi = i0+m*16+r16, rows gj = j0+n*16+kg*4+reg

  #pragma unroll
  for (int ks = 0; ks < 2; ++ks) {
    const int koff = ks * 32 + kg * 8;
    bf16x8 aH[2], aL[2], bH[2], bL[2];   // a = i-panel, b = j-panel
    #pragma unroll
    for (int m = 0; m < 2; ++m) {
      const size_t off = (size_t)(i0 + m * 16 + r16) * D_EMB + koff;
      aH[m] = *(const bf16x8*)(Mhi + off);
      aL[m] = *(const bf16x8*)(Mlo + off);
    }
    #pragma unroll
    for (int n = 0; n < 2; ++n) {
      const size_t off = (size_t)(j0 + n * 16 + r16) * D_EMB + koff;
      bH[n] = *(const bf16x8*)(Mhi + off);
      bL[n] = *(const bf16x8*)(Mlo + off);
    }
    #pragma unroll
    for (int m = 0; m < 2; ++m)
      #pragma unroll
      for (int n = 0; n < 2; ++n) {
        acc[m][n] = __builtin_amdgcn_mfma_f32_16x16x32_bf16(
            bH[n], aH[m], acc[m][n], 0, 0, 0);   // Hj.Hi
        acc[m][n] = __builtin_amdgcn_mfma_f32_16x16x32_bf16(
            bH[n], aL[m], acc[m][n], 0, 0, 0);   // Hj.Li
        acc[m][n] = __builtin_amdgcn_mfma_f32_16x16x32_bf16(
            bL[n], aH[m], acc[m][n], 0, 0, 0);   // Lj.Hi
      }
  }

  // ---- epilogue: distances + distortion partial sums, float4 D/nrm loads
  float rA[2];
  #pragma unroll
  for (int m = 0; m < 2; ++m) rA[m] = nrm[i0 + m * 16 + r16];

  float s1 = 0.f, s2 = 0.f, s3 = 0.f, s4 = 0.f;
  #pragma unroll
  for (int m = 0; m < 2; ++m) {
    const int gi = i0 + m * 16 + r16;            // D row for this lane/m
    const float* __restrict__ Drow = Dm + (size_t)gi * N_PTS;
    #pragma unroll
    for (int n = 0; n < 2; ++n) {
      const int gj0 = j0 + n * 16 + kg * 4;      // first of 4 consecutive cols
      const float4 Dv4 = *(const float4*)(Drow + gj0);
      const float4 rB4 = *(const float4*)(nrm + gj0);
      #pragma unroll
      for (int r = 0; r < 4; ++r) {
        const float Dv = (r == 0) ? Dv4.x : (r == 1) ? Dv4.y : (r == 2) ? Dv4.z : Dv4.w;
        const float rB = (r == 0) ? rB4.x : (r == 1) ? rB4.y : (r == 2) ? rB4.z : rB4.w;
        const float dot = acc[m][n][r];
        const float sq = fmaxf(rA[m] + rB - 2.f * dot, 0.f);
        float dd = __builtin_amdgcn_sqrtf(sq);
        const bool diag = (gi == gj0 + r);
        if (diag) dd = 0.f;                      // exact: ||x-x|| = 0
        const float denom = Dv + (diag ? 1.f : 0.f) + 1e-8f;
        const float rd = __builtin_amdgcn_rcpf(denom);
        const float av = dd * rd;                // a = d/denom
        const float bv = Dv * rd;                // b = D/denom
        s1 += av;
        s2 = fmaf(av, av, s2);
        s3 = fmaf(av, bv, s3);
        s4 = fmaf(bv, bv, s4);
      }
    }
  }

  // ---- wave shuffle reduce, one contention-free f64 write per wave
  #pragma unroll
  for (int off = 32; off > 0; off >>= 1) {
    s1 += __shfl_down(s1, off);
    s2 += __shfl_down(s2, off);
    s3 += __shfl_down(s3, off);
    s4 += __shfl_down(s4, off);
  }
  if (l == 0) {
    const int gw = ((blockIdx.y * gridDim.x + blockIdx.x) << 2) + w;
    part[0 * NWAVE + gw] = (double)s1;
    part[1 * NWAVE + gw] = (double)s2;
    part[2 * NWAVE + gw] = (double)s3;
    part[3 * NWAVE + gw] = (double)s4;
  }
}

// ---------------------------------------------------------------------------
// Reduce 4 x NWAVE partials; emit sum(dist) = s^2*S2 - 2 s S3 + S4, s=S1/S2.
// ---------------------------------------------------------------------------
__global__ __launch_bounds__(1024) void distortion_final(
    const double* __restrict__ part, float* __restrict__ out) {
  __shared__ double red[16][4];
  const int t = threadIdx.x;
  double s[4];
  #pragma unroll
  for (int k = 0; k < 4; ++k) {
    double v = 0.0;
    #pragma unroll
    for (int c = 0; c < NWAVE / 1024; ++c) v += part[k * NWAVE + c * 1024 + t];
    s[k] = v;
  }
  #pragma unroll
  for (int off = 32; off > 0; off >>= 1)
    #pragma unroll
    for (int k = 0; k < 4; ++k) s[k] += __shfl_down(s[k], off);
  const int w = t >> 6, l = t & 63;
  if (l == 0) {
    #pragma unroll
    for (int k = 0; k < 4; ++k) red[w][k] = s[k];
  }
  __syncthreads();
  if (t == 0) {
    double S0 = 0, S1 = 0, S2 = 0, S3 = 0;
    #pragma unroll
    for (int ww = 0; ww < 16; ++ww) {
      S0 += red[ww][0]; S1 += red[ww][1]; S2 += red[ww][2]; S3 += red[ww][3];
    }
    const double sc = S0 / S1;
    const double r = (sc * sc * S1 - 2.0 * sc * S2 + S3) /
                     ((double)N_PTS * (double)N_PTS - (double)N_PTS);
    out[0] = (float)r;
  }
}

extern "C" void kernel_launch(void* const* d_in, const int* in_sizes, int n_in,
                              void* d_out, int out_size, void* d_ws, size_t ws_size,
                              hipStream_t stream) {
  const float* mapping = (const float*)d_in[0];
  const float* Dm = (const float*)d_in[1];
  float* out = (float*)d_out;
  // ws layout: nrm 16KB | part 512KB | Mhi 512KB | Mlo 512KB  (~1.6 MB)
  float* nrm = (float*)d_ws;
  double* part = (double*)((char*)d_ws + 16384);
  ushort* Mhi = (ushort*)((char*)d_ws + 16384 + 524288);
  ushort* Mlo = (ushort*)((char*)d_ws + 16384 + 524288 + 524288);

  prep_kernel<<<dim3(N_PTS), dim3(64), 0, stream>>>(mapping, Mhi, Mlo, nrm);
  distortion_main<<<dim3(N_PTS / BTILE, N_PTS / BTILE), dim3(256), 0, stream>>>(
      Mhi, Mlo, Dm, nrm, part);
  distortion_final<<<1, 1024, 0, stream>>>(part, out);
}

// Round 10
// 34.177 us; speedup vs baseline: 1.7696x; 1.7696x over previous
//
#include <hip/hip_runtime.h>
#include <hip/hip_bf16.h>

#define N_PTS 4096
#define D_EMB 64
#define TILE  128
#define KH    32                                        // K staged in halves
#define NWAVE ((N_PTS / TILE) * (N_PTS / TILE) * 4)     // 4096 waves

typedef __attribute__((ext_vector_type(8))) short bf16x8;  // 8 bf16 = 4 VGPR
typedef __attribute__((ext_vector_type(4))) float f32x4;   // MFMA 16x16 acc

// ---------------------------------------------------------------------------
// Fused prep: bf16 hi/lo split + exact f32 row squared-norms.
// ---------------------------------------------------------------------------
__global__ void prep_kernel(const float* __restrict__ mapping,
                            ushort* __restrict__ Mhi,
                            ushort* __restrict__ Mlo,
                            float* __restrict__ nrm) {
  const int row = blockIdx.x;
  const int l = threadIdx.x;          // 0..63
  const int idx = row * D_EMB + l;
  const float x = mapping[idx];
  __hip_bfloat16 h = __float2bfloat16(x);
  const float hf = __bfloat162float(h);
  __hip_bfloat16 lo = __float2bfloat16(x - hf);
  Mhi[idx] = *reinterpret_cast<ushort*>(&h);
  Mlo[idx] = *reinterpret_cast<ushort*>(&lo);
  float s = x * x;
  #pragma unroll
  for (int off = 32; off > 0; off >>= 1) s += __shfl_down(s, off);
  if (l == 0) nrm[row] = s;
}

// ---------------------------------------------------------------------------
// MFMA gram + fused distortion, all-dense global access.
// dot = Hj.Hi + Hj.Li + Lj.Hi (Li.Lj dropped; absmax 0.0 since R6).
//
// R6-R9 post-mortem: every global access was a 16-row scatter (MFMA frag
// loads from global; D loads through the C-fragment layout) -> per-CU
// vector-memory transaction pipe serialized at ~16 line-transactions per
// instr; occupancy/width fixes moved nothing. THIS round:
//  (a) panels staged to LDS via global_load_lds (dense), frags via
//      ds_read_b128 (XOR chunk swizzle c^=(r&3), conflict-minimal);
//  (b) gram dumped to per-wave-private LDS (swizzle cw^=(i&7)), epilogue
//      reads D in row-burst float4 (4 rows x 256B contiguous, full lines);
//      two 32-row halves keep LDS at 32KB total -> 5 blocks/CU LDS cap.
// R7 lesson: frag loads of a k-step issued together, never phased.
// R5 lesson: contention-free per-wave partial writes (NO atomics).
// R2/R3 lesson: no min-waves launch_bounds arg.
// ---------------------------------------------------------------------------
__global__ __launch_bounds__(256) void distortion_main(
    const ushort* __restrict__ Mhi, const ushort* __restrict__ Mlo,
    const float* __restrict__ Dm, const float* __restrict__ nrm,
    double* __restrict__ part) {
  __shared__ __align__(16) char smem[32768];   // panels, then gram halves
  ushort* span = (ushort*)smem;   // AH|AL|BH|BL, each 128 rows x 4 chunks x 8 ush
  float*  sg   = (float*)smem;    // per-wave 32x64 gram half (8KB each)

  const int t = threadIdx.x;
  const int w = t >> 6, l = t & 63;
  const int r16 = l & 15;        // fragment row/col within 16
  const int kg  = l >> 4;        // k-group 0..3
  const int wr = w >> 1, wc = w & 1;
  const int i0 = blockIdx.y * TILE;
  const int j0 = blockIdx.x * TILE;

  f32x4 acc[4][4] = {};  // swapped: rows gj = wc*64+n*16+kg*4+reg, cols gi = wr*64+m*16+r16

  for (int h = 0; h < 2; ++h) {
    if (h) __syncthreads();      // WAR: panel overwrite
    // ---- stage 4 sub-panels (32KB) dense: slot s=q*256+t; LDS linear,
    //      source chunk pre-swizzled c = cs ^ (r&3)  (involution)
    #pragma unroll
    for (int q = 0; q < 8; ++q) {
      const int s   = q * 256 + t;
      const int p   = s >> 9;          // 0 AH, 1 AL, 2 BH, 3 BL
      const int sp_ = s & 511;
      const int r   = sp_ >> 2;        // panel row 0..127
      const int cs  = sp_ & 3;         // stored chunk
      const int c   = cs ^ (r & 3);    // source chunk
      const ushort* base = (p == 0 || p == 2) ? Mhi : Mlo;
      const int row = ((p < 2) ? i0 : j0) + r;
      const ushort* g = base + (size_t)row * D_EMB + h * KH + c * 8;
      char* ldst = smem + (q * 256 + w * 64) * 16;   // wave-uniform + lane*16
      __builtin_amdgcn_global_load_lds(
          (const __attribute__((address_space(1))) void*)g,
          (__attribute__((address_space(3))) void*)ldst, 16, 0, 0);
    }
    __syncthreads();

    // ---- fragments from LDS (all loaded up-front), MFMA
    bf16x8 aH[4], aL[4], bH[4], bL[4];
    #pragma unroll
    for (int m = 0; m < 4; ++m) {
      const int r = wr * 64 + m * 16 + r16;
      const int cc = kg ^ (r & 3);
      aH[m] = *(const bf16x8*)(span + 0 * 4096 + r * 32 + cc * 8);
      aL[m] = *(const bf16x8*)(span + 1 * 4096 + r * 32 + cc * 8);
    }
    #pragma unroll
    for (int n = 0; n < 4; ++n) {
      const int r = wc * 64 + n * 16 + r16;
      const int cc = kg ^ (r & 3);
      bH[n] = *(const bf16x8*)(span + 2 * 4096 + r * 32 + cc * 8);
      bL[n] = *(const bf16x8*)(span + 3 * 4096 + r * 32 + cc * 8);
    }
    #pragma unroll
    for (int m = 0; m < 4; ++m)
      #pragma unroll
      for (int n = 0; n < 4; ++n) {
        acc[m][n] = __builtin_amdgcn_mfma_f32_16x16x32_bf16(
            bH[n], aH[m], acc[m][n], 0, 0, 0);   // Hj.Hi
        acc[m][n] = __builtin_amdgcn_mfma_f32_16x16x32_bf16(
            bH[n], aL[m], acc[m][n], 0, 0, 0);   // Hj.Li
        acc[m][n] = __builtin_amdgcn_mfma_f32_16x16x32_bf16(
            bL[n], aH[m], acc[m][n], 0, 0, 0);   // Lj.Hi
      }
  }

  __syncthreads();   // all frag reads done; gram regions may overwrite panels

  // ---- per-wave epilogue: dump gram half to private LDS, read D dense
  const int jc   = l & 15;       // float4 chunk within wave's 64 cols
  const int isub = l >> 4;       // row-within-iter 0..3
  const int gj0  = j0 + wc * 64 + jc * 4;
  const float4 rB4 = *(const float4*)(nrm + gj0);

  float s1 = 0.f, s2 = 0.f, s3 = 0.f, s4 = 0.f;
  #pragma unroll
  for (int half = 0; half < 2; ++half) {
    // dump: m in {2*half, 2*half+1}; chunk swizzle cw ^= (i_w&7)
    #pragma unroll
    for (int mm = 0; mm < 2; ++mm) {
      const int m = half * 2 + mm;
      const int i_w = m * 16 + r16;
      const int i_h = i_w & 31;
      #pragma unroll
      for (int n = 0; n < 4; ++n) {
        const int cw = (n * 4 + kg) ^ (i_w & 7);
        *(f32x4*)(sg + w * 2048 + i_h * 64 + cw * 4) = acc[m][n];
      }
    }
    // epilogue: 8 iters x 4 rows; D float4 = 4 rows x 256B dense bursts
    #pragma unroll
    for (int it = 0; it < 8; ++it) {
      const int i_h = it * 4 + isub;
      const int gi = i0 + wr * 64 + half * 32 + i_h;
      const float rA = nrm[gi];
      const float4 Dv4 = *(const float4*)(Dm + (size_t)gi * N_PTS + gj0);
      const float4 g4 = *(const float4*)(sg + w * 2048 + i_h * 64 +
                                         ((jc ^ (i_h & 7)) * 4));
      #pragma unroll
      for (int r = 0; r < 4; ++r) {
        const float Dv = (r == 0) ? Dv4.x : (r == 1) ? Dv4.y : (r == 2) ? Dv4.z : Dv4.w;
        const float rB = (r == 0) ? rB4.x : (r == 1) ? rB4.y : (r == 2) ? rB4.z : rB4.w;
        const float dot = (r == 0) ? g4.x : (r == 1) ? g4.y : (r == 2) ? g4.z : g4.w;
        const float sq = fmaxf(rA + rB - 2.f * dot, 0.f);
        float dd = __builtin_amdgcn_sqrtf(sq);
        const bool diag = (gi == gj0 + r);
        if (diag) dd = 0.f;                      // exact: ||x-x|| = 0
        const float denom = Dv + (diag ? 1.f : 0.f) + 1e-8f;
        const float rd = __builtin_amdgcn_rcpf(denom);
        const float av = dd * rd;                // a = d/denom
        const float bv = Dv * rd;                // b = D/denom
        s1 += av;
        s2 = fmaf(av, av, s2);
        s3 = fmaf(av, bv, s3);
        s4 = fmaf(bv, bv, s4);
      }
    }
  }

  // ---- wave shuffle reduce, one contention-free f64 write per wave
  #pragma unroll
  for (int off = 32; off > 0; off >>= 1) {
    s1 += __shfl_down(s1, off);
    s2 += __shfl_down(s2, off);
    s3 += __shfl_down(s3, off);
    s4 += __shfl_down(s4, off);
  }
  if (l == 0) {
    const int gw = ((blockIdx.y * gridDim.x + blockIdx.x) << 2) + w;
    part[0 * NWAVE + gw] = (double)s1;
    part[1 * NWAVE + gw] = (double)s2;
    part[2 * NWAVE + gw] = (double)s3;
    part[3 * NWAVE + gw] = (double)s4;
  }
}

// ---------------------------------------------------------------------------
// Reduce 4 x NWAVE partials; emit sum(dist) = s^2*S2 - 2 s S3 + S4, s=S1/S2.
// ---------------------------------------------------------------------------
__global__ __launch_bounds__(1024) void distortion_final(
    const double* __restrict__ part, float* __restrict__ out) {
  __shared__ double red[16][4];
  const int t = threadIdx.x;
  double s[4];
  #pragma unroll
  for (int k = 0; k < 4; ++k) {
    double v = 0.0;
    #pragma unroll
    for (int c = 0; c < NWAVE / 1024; ++c) v += part[k * NWAVE + c * 1024 + t];
    s[k] = v;
  }
  #pragma unroll
  for (int off = 32; off > 0; off >>= 1)
    #pragma unroll
    for (int k = 0; k < 4; ++k) s[k] += __shfl_down(s[k], off);
  const int w = t >> 6, l = t & 63;
  if (l == 0) {
    #pragma unroll
    for (int k = 0; k < 4; ++k) red[w][k] = s[k];
  }
  __syncthreads();
  if (t == 0) {
    double S0 = 0, S1 = 0, S2 = 0, S3 = 0;
    #pragma unroll
    for (int ww = 0; ww < 16; ++ww) {
      S0 += red[ww][0]; S1 += red[ww][1]; S2 += red[ww][2]; S3 += red[ww][3];
    }
    const double sc = S0 / S1;
    const double r = (sc * sc * S1 - 2.0 * sc * S2 + S3) /
                     ((double)N_PTS * (double)N_PTS - (double)N_PTS);
    out[0] = (float)r;
  }
}

extern "C" void kernel_launch(void* const* d_in, const int* in_sizes, int n_in,
                              void* d_out, int out_size, void* d_ws, size_t ws_size,
                              hipStream_t stream) {
  const float* mapping = (const float*)d_in[0];
  const float* Dm = (const float*)d_in[1];
  float* out = (float*)d_out;
  // ws layout: nrm 16KB | part 128KB | Mhi 512KB | Mlo 512KB  (~1.2 MB)
  float* nrm = (float*)d_ws;
  double* part = (double*)((char*)d_ws + 16384);
  ushort* Mhi = (ushort*)((char*)d_ws + 16384 + 131072);
  ushort* Mlo = (ushort*)((char*)d_ws + 16384 + 131072 + 524288);

  prep_kernel<<<dim3(N_PTS), dim3(64), 0, stream>>>(mapping, Mhi, Mlo, nrm);
  distortion_main<<<dim3(N_PTS / TILE, N_PTS / TILE), dim3(256), 0, stream>>>(
      Mhi, Mlo, Dm, nrm, part);
  distortion_final<<<1, 1024, 0, stream>>>(part, out);
}